// Round 6
// baseline (165.724 us; speedup 1.0000x reference)
//
#include <hip/hip_runtime.h>
#include <hip/hip_bf16.h>
#include <hip/hip_fp16.h>
#include <stdint.h>

// Problem constants
#define NBATCH 4
#define SEQ    2048
#define DIM    1024

typedef __attribute__((ext_vector_type(8))) __bf16 bf16x8;
typedef __attribute__((ext_vector_type(4))) float  f32x4;

// Workspace layout (bytes)
#define OFF_XBF   (0ull)                         // 16 MiB
#define OFF_WBF   (16777216ull)                  //  6 MiB  [3072][1024] bf16
#define OFF_Q     (23068672ull)                  // 16 MiB (pre-scaled by 1/32)
#define OFF_K     (39845888ull)                  // 16 MiB
#define OFF_VT    (56623104ull)                  // 16 MiB  V^T per batch [DIM][SEQ]
#define OFF_SC    (73400320ull)                  // 32 MiB fp16 scores
#define OFF_P     (140509184ull)                 // 32 MiB bf16 probs

__device__ __forceinline__ uint16_t f2bf(float f) {
  uint32_t u = __float_as_uint(f);
  u = (u + 0x7fffu + ((u >> 16) & 1u)) >> 16;   // RTN-even
  return (uint16_t)u;
}

// ---------------- fused converts: X (blocks 0..8191), W (blocks 8192..11263) --
__global__ __launch_bounds__(256) void k_convert(const float* __restrict__ X,
                                                 const float* __restrict__ Wq,
                                                 const float* __restrict__ Wk,
                                                 const float* __restrict__ Wv,
                                                 uint16_t* __restrict__ Xbf,
                                                 uint16_t* __restrict__ Wbf) {
  int id = blockIdx.x;
  if (id < 8192) {
    int i = id * 256 + threadIdx.x;
    float4 v = ((const float4*)X)[i];
    ushort4 o;
    o.x = f2bf(v.x); o.y = f2bf(v.y); o.z = f2bf(v.z); o.w = f2bf(v.w);
    ((ushort4*)Xbf)[i] = o;
  } else {
    int j = id - 8192;                    // 0..3071
    int g = j >> 10;
    const float* W = (g == 0) ? Wq : (g == 1) ? Wk : Wv;
    float scale = (g == 0) ? 0.03125f : 1.0f;   // fold 1/sqrt(1024) into W_q
    int i = (j & 1023) * 256 + threadIdx.x;
    float4 v = ((const float4*)W)[i];
    ushort4 o;
    o.x = f2bf(v.x * scale); o.y = f2bf(v.y * scale);
    o.z = f2bf(v.z * scale); o.w = f2bf(v.w * scale);
    ((ushort4*)(Wbf + (size_t)g * 1048576))[i] = o;
  }
}

// ---------------- common helpers ----------------
// LDS rows are 64 bf16 = 128B; XOR swizzle byte ^= (row&7)<<4; inverse applied
// to the global SOURCE slot (global_load_lds writes linearly).

__device__ __forceinline__ void gll16(const void* g, void* l) {
  __builtin_amdgcn_global_load_lds((const __attribute__((address_space(1))) void*)g,
                                   (__attribute__((address_space(3))) void*)l, 16, 0, 0);
}

__device__ __forceinline__ bf16x8 frag_ld(const char* lds, int row, int kbyte) {
  int bo = row * 128 + kbyte;
  bo ^= (row & 7) << 4;
  return *(const bf16x8*)(lds + bo);
}

#define VM_WAIT8() asm volatile("s_waitcnt vmcnt(8)" ::: "memory")
#define VM_WAIT3() asm volatile("s_waitcnt vmcnt(3)" ::: "memory")
#define VM_WAIT0() asm volatile("s_waitcnt vmcnt(0)" ::: "memory")
#define RAW_BAR()  asm volatile("s_barrier" ::: "memory")

// ============================================================================
// k_qkv: fused 8192x3072 GEMM, 128(M)x256(N) tile, BK=64, 512 thr (8 waves,
// 2M x 4N), fine-grained 2-phase schedule, counted vmcnt(3) (never drained in
// steady state). LDS 96KB = 2 buf x (A 16KB + B 32KB); 1 block/CU, 2 w/SIMD.
//
// Stage ledger (sweep = 1 load/thread = 8KB; 6 sweeps per K-tile):
//   Ph1(t): reads av[0-3],bv[0-1] from buf; stages Bf23/Bb01/Bb23(t+1)->nbuf
//           [nbuf idle during tile t -> no WAR]                       [t<=14]
//   Ph2(t): reads bv[2-3] from buf(B-backs); stages A(t+2)x2+Bf01(t+2)->buf
//           [A & B-fronts fully read in Ph1, all waves past Ph1 end-bar]
//           then vmcnt(3): retires tile(t+1)'s 6 sweeps (Ph2(t-1)+Ph1(t)),
//           leaves this phase's 3 in flight                           [t<=13]
//   t==14: vmcnt(0) drains tile-15 finals; t>=14/15: stages skipped.
//   Every stage target's old content last read >= 1 barrier earlier (the R3
//   bug was violating exactly this). Barriers unconditional -> no hang.
// ============================================================================

// 2-sweep A stage: 128 rows x 64 bf16 (16KB), linear LDS, source slot-swizzled
__device__ __forceinline__ void sweepA(const uint16_t* __restrict__ Ab, int kt,
                                       int t, char* ldsA) {
#pragma unroll
  for (int c = 0; c < 2; ++c) {
    int L = c * 8192 + t * 16;
    int row = L >> 7;
    int slot = (t & 7) ^ (row & 7);
    gll16((const void*)(Ab + (size_t)row * DIM + kt * 64 + slot * 8),
          (void*)(ldsA + L));
  }
}
// 1-sweep B stage: strips {sb, sb+1}, rows off..off+31 of each 64-row strip
__device__ __forceinline__ void sweepB(const uint16_t* __restrict__ Bb, int kt,
                                       int t, char* ldsB, int sb, int off) {
  int strip = sb + (t >> 8);
  int rl = (t >> 3) & 31;
  int grow = strip * 64 + off + rl;
  int slot = (t & 7) ^ (grow & 7);
  gll16((const void*)(Bb + (size_t)grow * DIM + kt * 64 + slot * 8),
        (void*)(ldsB + grow * 128 + (t & 7) * 16));
}

__global__ __launch_bounds__(512, 2) void k_qkv(const uint16_t* __restrict__ Xbf,
                                                const uint16_t* __restrict__ Wbf,
                                                uint16_t* __restrict__ Qb,
                                                uint16_t* __restrict__ Kb,
                                                uint16_t* __restrict__ Vt) {
  extern __shared__ char lds[];                 // 98304 bytes
  char* A0 = lds;           char* B0 = lds + 16384;
  char* A1 = lds + 49152;   char* B1 = lds + 65536;

  const int t = threadIdx.x;
  const int lane = t & 63;
  const int wid = t >> 6;
  const int wm = wid >> 2;                      // 0..1 (64-row strip of M=128)
  const int wn = wid & 3;                       // 0..3 (64-col strip of N=256)
  const int frow = lane & 15;
  const int fk16 = (lane >> 4) * 16;

  // grid 768 = 64 m-tiles x 12 n-tiles, m-FASTEST (keeps the XCD m-residue
  // L2 property that holds FETCH at ~47MB; R4 proved swizzling breaks it)
  int id = blockIdx.x;
  const int mt = id & 63, nt = id >> 6;
  const int m0 = mt * 128, n0 = nt * 256;
  const int g = n0 >> 10, ncol = n0 & 1023;

  const uint16_t* A  = Xbf + (size_t)m0 * DIM;
  const uint16_t* Bm = Wbf + (size_t)n0 * DIM;  // Wbf as [3072][1024]

  f32x4 acc[4][4];
#pragma unroll
  for (int i = 0; i < 4; ++i)
#pragma unroll
    for (int j = 0; j < 4; ++j) acc[i][j] = (f32x4){0.f, 0.f, 0.f, 0.f};

  // prologue: tile0 full (6 sweeps) + tile1 first batch (3 sweeps)
  sweepA(A, 0, t, A0);
  sweepB(Bm, 0, t, B0, 0, 0);  sweepB(Bm, 0, t, B0, 2, 0);
  sweepB(Bm, 0, t, B0, 0, 32); sweepB(Bm, 0, t, B0, 2, 32);
  sweepA(A, 1, t, A1);
  sweepB(Bm, 1, t, B1, 0, 0);
  VM_WAIT3(); RAW_BAR();                        // tile0 visible; tile1 batch in flight

#pragma unroll 1
  for (int kt = 0; kt < 16; ++kt) {
    char* cA = (kt & 1) ? A1 : A0;
    char* cB = (kt & 1) ? B1 : B0;
    char* nB = (kt & 1) ? B0 : B1;

    // ---- Phase 1: read av[0-3], bv[0-1]; stage tile(t+1) finals -> nbuf ----
    bf16x8 av[4][2], bv01[2][2];
#pragma unroll
    for (int mi = 0; mi < 4; ++mi)
#pragma unroll
      for (int ki = 0; ki < 2; ++ki)
        av[mi][ki] = frag_ld(cA, wm * 64 + mi * 16 + frow, ki * 64 + fk16);
#pragma unroll
    for (int ni = 0; ni < 2; ++ni)
#pragma unroll
      for (int ki = 0; ki < 2; ++ki)
        bv01[ni][ki] = frag_ld(cB, wn * 64 + ni * 16 + frow, ki * 64 + fk16);
    if (kt <= 14) {
      sweepB(Bm, kt + 1, t, nB, 2, 0);
      sweepB(Bm, kt + 1, t, nB, 0, 32);
      sweepB(Bm, kt + 1, t, nB, 2, 32);
    }
    RAW_BAR();
    __builtin_amdgcn_s_setprio(1);
#pragma unroll
    for (int mi = 0; mi < 4; ++mi)
#pragma unroll
      for (int ni = 0; ni < 2; ++ni)
#pragma unroll
        for (int ki = 0; ki < 2; ++ki)
          acc[mi][ni] = __builtin_amdgcn_mfma_f32_16x16x32_bf16(av[mi][ki], bv01[ni][ki],
                                                                acc[mi][ni], 0, 0, 0);
    __builtin_amdgcn_s_setprio(0);
    RAW_BAR();

    // ---- Phase 2: read bv[2-3]; stage tile(t+2) A + Bf01 -> cur buf ----
    bf16x8 bv23[2][2];
#pragma unroll
    for (int ni = 0; ni < 2; ++ni)
#pragma unroll
      for (int ki = 0; ki < 2; ++ki)
        bv23[ni][ki] = frag_ld(cB, wn * 64 + (2 + ni) * 16 + frow, ki * 64 + fk16);
    if (kt <= 13) {
      sweepA(A, kt + 2, t, cA);                 // A(kt) fully read in Ph1
      sweepB(Bm, kt + 2, t, cB, 0, 0);          // Bf01(kt) fully read in Ph1
    }
    if (kt <= 13)      { VM_WAIT3(); }          // retires tile(t+1)'s 6 sweeps
    else if (kt == 14) { VM_WAIT0(); }          // drain tile-15 finals
    RAW_BAR();
    __builtin_amdgcn_s_setprio(1);
#pragma unroll
    for (int mi = 0; mi < 4; ++mi)
#pragma unroll
      for (int ni = 0; ni < 2; ++ni)
#pragma unroll
        for (int ki = 0; ki < 2; ++ki)
          acc[mi][2 + ni] = __builtin_amdgcn_mfma_f32_16x16x32_bf16(av[mi][ki], bv23[ni][ki],
                                                                    acc[mi][2 + ni], 0, 0, 0);
    __builtin_amdgcn_s_setprio(0);
    RAW_BAR();
  }

  const int rbase = wm * 64 + (lane >> 4) * 4;  // C row = (lane>>4)*4 + reg
  const int cbase = wn * 64 + (lane & 15);      // C col = lane&15

  if (g < 2) {
    uint16_t* out = (g == 0) ? Qb : Kb;
#pragma unroll
    for (int mi = 0; mi < 4; ++mi)
#pragma unroll
      for (int ni = 0; ni < 4; ++ni) {
        int c = ncol + cbase + ni * 16;
#pragma unroll
        for (int r = 0; r < 4; ++r) {
          int m = m0 + rbase + mi * 16 + r;
          out[(size_t)m * DIM + c] = f2bf(acc[mi][ni][r]);
        }
      }
  } else {
    // write V transposed: Vt[b][e][s]
    const int b = m0 >> 11, sl = m0 & 2047;
#pragma unroll
    for (int mi = 0; mi < 4; ++mi)
#pragma unroll
      for (int ni = 0; ni < 4; ++ni) {
        int e = ncol + cbase + ni * 16;
        int s = sl + rbase + mi * 16;
        ushort4 o;
        o.x = f2bf(acc[mi][ni][0]); o.y = f2bf(acc[mi][ni][1]);
        o.z = f2bf(acc[mi][ni][2]); o.w = f2bf(acc[mi][ni][3]);
        *(ushort4*)(Vt + ((size_t)b * DIM + e) * SEQ + s) = o;
      }
  }
}

// ---------------- 128^2 GEMM core: 2-deep counted-vmcnt pipeline -------------
__device__ __forceinline__ void stage_tile(const uint16_t* __restrict__ g, int ld,
                                           int t, char* lds) {
#pragma unroll
  for (int c = 0; c < 4; ++c) {
    int L = c * 4096 + t * 16;
    int row = L >> 7;
    int slot = (t & 7) ^ (row & 7);
    gll16((const void*)(g + (size_t)row * ld + slot * 8), (void*)(lds + L));
  }
}

__device__ __forceinline__ void gemm_loop(const uint16_t* __restrict__ A, int lda,
                                          const uint16_t* __restrict__ Bm, int ldb,
                                          int ksteps, char* lds, f32x4 acc[4][4]) {
  char* lA0 = lds;          char* lA1 = lds + 16384;
  char* lB0 = lds + 32768;  char* lB1 = lds + 49152;
  const int t = threadIdx.x;
  const int lane = t & 63;
  const int wm = (t >> 6) & 1;
  const int wn = t >> 7;
  const int frow = lane & 15;
  const int fk16 = (lane >> 4) * 16;

  stage_tile(A,      lda, t, lA0); stage_tile(Bm,      ldb, t, lB0);
  if (ksteps > 1) { stage_tile(A + 64, lda, t, lA1); stage_tile(Bm + 64, ldb, t, lB1); }

  for (int kt = 0; kt < ksteps; ++kt) {
    if (kt == ksteps - 1) { VM_WAIT0(); } else { VM_WAIT8(); }
    RAW_BAR();
    const char* cA = (kt & 1) ? lA1 : lA0;
    const char* cB = (kt & 1) ? lB1 : lB0;
#pragma unroll
    for (int ki = 0; ki < 2; ++ki) {
      bf16x8 av[4], bv[4];
#pragma unroll
      for (int mi = 0; mi < 4; ++mi)
        av[mi] = frag_ld(cA, wm * 64 + mi * 16 + frow, ki * 64 + fk16);
#pragma unroll
      for (int ni = 0; ni < 4; ++ni)
        bv[ni] = frag_ld(cB, wn * 64 + ni * 16 + frow, ki * 64 + fk16);
      __builtin_amdgcn_s_setprio(1);
#pragma unroll
      for (int mi = 0; mi < 4; ++mi)
#pragma unroll
        for (int ni = 0; ni < 4; ++ni)
          acc[mi][ni] = __builtin_amdgcn_mfma_f32_16x16x32_bf16(av[mi], bv[ni],
                                                                acc[mi][ni], 0, 0, 0);
      __builtin_amdgcn_s_setprio(0);
    }
    RAW_BAR();
    if (kt + 2 < ksteps) {
      stage_tile(A  + (kt + 2) * 64, lda, t, (kt & 1) ? lA1 : lA0);
      stage_tile(Bm + (kt + 2) * 64, ldb, t, (kt & 1) ? lB1 : lB0);
    }
  }
}

// ---------------- causal scores: Sc = Q K^T (lower-tri 128x128 tiles, fp16) --
__global__ __launch_bounds__(256) void k_scores(const uint16_t* __restrict__ Qb,
                                                const uint16_t* __restrict__ Kb,
                                                __half* __restrict__ Sc) {
  __shared__ __align__(16) char lds[65536];
  int x = blockIdx.x;                 // 0..543
  int b = x / 136, tr = x % 136;
  int qt = 0;
  while ((qt + 1) * (qt + 2) / 2 <= tr) ++qt;
  int kt = tr - qt * (qt + 1) / 2;

  f32x4 acc[4][4];
#pragma unroll
  for (int i = 0; i < 4; ++i)
#pragma unroll
    for (int j = 0; j < 4; ++j) acc[i][j] = (f32x4){0.f, 0.f, 0.f, 0.f};

  const uint16_t* A = Qb + ((size_t)b * SEQ + qt * 128) * DIM;
  const uint16_t* Bm = Kb + ((size_t)b * SEQ + kt * 128) * DIM;
  gemm_loop(A, DIM, Bm, DIM, DIM / 64, lds, acc);

  const int lane = threadIdx.x & 63;
  const int wm = (threadIdx.x >> 6) & 1, wn = threadIdx.x >> 7;
  const int rbase = qt * 128 + wm * 64 + (lane >> 4) * 4;
  const int cbase = kt * 128 + wn * 64 + (lane & 15);
  __half* out = Sc + (size_t)b * SEQ * SEQ;
#pragma unroll
  for (int mi = 0; mi < 4; ++mi)
#pragma unroll
    for (int ni = 0; ni < 4; ++ni) {
      int c = cbase + ni * 16;
#pragma unroll
      for (int r = 0; r < 4; ++r)
        out[(size_t)(rbase + mi * 16 + r) * SEQ + c] = __float2half(acc[mi][ni][r]);
    }
}

// ---------------- row softmax: one WAVE per row, fp16 row in registers -------
struct h4 { __half2 a, b; };          // 8 bytes = 4 halves

__global__ __launch_bounds__(256) void k_softmax(const __half* __restrict__ Sc,
                                                 uint16_t* __restrict__ P) {
  int gid = blockIdx.x * 4 + (threadIdx.x >> 6);
  int lane = threadIdx.x & 63;
  int b = gid >> 11, q = gid & 2047;
  const __half* srow = Sc + ((size_t)b * SEQ + q) * SEQ;
  uint16_t* prow = P + ((size_t)b * SEQ + q) * SEQ;
  int nv = q + 1;
  int kpad = ((q >> 7) + 1) << 7;     // PV reads exactly [0, kpad)
  int niter = (kpad + 255) >> 8;      // 256 halves per wave-iter

  float4 v[8];
  const h4* src = (const h4*)srow;
#pragma unroll
  for (int i = 0; i < 8; ++i) {
    if (i < niter) {
      int idx = lane + (i << 6);
      h4 raw = src[idx];
      float2 fa = __half22float2(raw.a), fb = __half22float2(raw.b);
      int k0 = idx << 2;
      float4 x;
      x.x = (k0 + 0 < nv) ? fa.x : -1e38f;
      x.y = (k0 + 1 < nv) ? fa.y : -1e38f;
      x.z = (k0 + 2 < nv) ? fb.x : -1e38f;
      x.w = (k0 + 3 < nv) ? fb.y : -1e38f;
      v[i] = x;
    } else {
      v[i] = make_float4(-1e38f, -1e38f, -1e38f, -1e38f);
    }
  }
  float m = -1e38f;
#pragma unroll
  for (int i = 0; i < 8; ++i)
    m = fmaxf(m, fmaxf(fmaxf(v[i].x, v[i].y), fmaxf(v[i].z, v[i].w)));
#pragma unroll
  for (int o = 32; o > 0; o >>= 1) m = fmaxf(m, __shfl_xor(m, o));

  float s = 0.f;
#pragma unroll
  for (int i = 0; i < 8; ++i) {
    v[i].x = __expf(v[i].x - m); v[i].y = __expf(v[i].y - m);
    v[i].z = __expf(v[i].z - m); v[i].w = __expf(v[i].w - m);
    s += v[i].x + v[i].y + v[i].z + v[i].w;
  }
#pragma unroll
  for (int o = 32; o > 0; o >>= 1) s += __shfl_xor(s, o);
  float inv = 1.0f / s;

  ushort4* dst = (ushort4*)prow;
#pragma unroll
  for (int i = 0; i < 8; ++i) {
    if (i < niter) {
      int idx = lane + (i << 6);
      if ((idx << 2) < kpad) {
        ushort4 o;
        o.x = f2bf(v[i].x * inv); o.y = f2bf(v[i].y * inv);
        o.z = f2bf(v[i].z * inv); o.w = f2bf(v[i].w * inv);
        dst[idx] = o;
      }
    }
  }
}

// ---------------- PV: O = P V  (A=P, B=Vt rows=e, cols=k) ----------------
__global__ __launch_bounds__(256) void k_pv(const uint16_t* __restrict__ P,
                                            const uint16_t* __restrict__ Vt,
                                            float* __restrict__ O) {
  __shared__ __align__(16) char lds[65536];
  int x = blockIdx.x;                 // 512
  int b = x >> 7, r7 = x & 127;
  int qt = 15 - (r7 >> 3);            // descending: big K-loops dispatch first
  int et = r7 & 7;

  f32x4 acc[4][4];
#pragma unroll
  for (int i = 0; i < 4; ++i)
#pragma unroll
    for (int j = 0; j < 4; ++j) acc[i][j] = (f32x4){0.f, 0.f, 0.f, 0.f};

  const uint16_t* A = P + (size_t)b * SEQ * SEQ + (size_t)qt * 128 * SEQ;
  const uint16_t* Bm = Vt + (size_t)b * DIM * SEQ + (size_t)et * 128 * SEQ;
  gemm_loop(A, SEQ, Bm, SEQ, (qt + 1) * 2, lds, acc);

  const int lane = threadIdx.x & 63;
  const int wm = (threadIdx.x >> 6) & 1, wn = threadIdx.x >> 7;
  const int rbase = qt * 128 + wm * 64 + (lane >> 4) * 4;
  const int cbase = et * 128 + wn * 64 + (lane & 15);
  float* out = O + (size_t)b * SEQ * DIM;
#pragma unroll
  for (int mi = 0; mi < 4; ++mi)
#pragma unroll
    for (int ni = 0; ni < 4; ++ni) {
      int c = cbase + ni * 16;
#pragma unroll
      for (int r = 0; r < 4; ++r)
        out[(size_t)(rbase + mi * 16 + r) * DIM + c] = acc[mi][ni][r];
    }
}

extern "C" void kernel_launch(void* const* d_in, const int* in_sizes, int n_in,
                              void* d_out, int out_size, void* d_ws, size_t ws_size,
                              hipStream_t stream) {
  const float* X  = (const float*)d_in[0];
  const float* Wq = (const float*)d_in[1];
  const float* Wk = (const float*)d_in[2];
  const float* Wv = (const float*)d_in[3];
  char* ws = (char*)d_ws;
  uint16_t* Xbf = (uint16_t*)(ws + OFF_XBF);
  uint16_t* Wbf = (uint16_t*)(ws + OFF_WBF);
  uint16_t* Qb  = (uint16_t*)(ws + OFF_Q);
  uint16_t* Kb  = (uint16_t*)(ws + OFF_K);
  uint16_t* Vt  = (uint16_t*)(ws + OFF_VT);
  __half*   Sc  = (__half*)(ws + OFF_SC);
  uint16_t* P   = (uint16_t*)(ws + OFF_P);
  float*    O   = (float*)d_out;

  k_convert<<<11264, 256, 0, stream>>>(X, Wq, Wk, Wv, Xbf, Wbf);
  k_qkv<<<768, 512, 98304, stream>>>(Xbf, Wbf, Qb, Kb, Vt);
  k_scores<<<544, 256, 0, stream>>>(Qb, Kb, Sc);
  k_softmax<<<2048, 256, 0, stream>>>(Sc, P);
  k_pv<<<512, 256, 0, stream>>>(P, Vt, O);
}

// Round 7
// 161.819 us; speedup vs baseline: 1.0241x; 1.0241x over previous
//
#include <hip/hip_runtime.h>
#include <hip/hip_bf16.h>
#include <hip/hip_fp16.h>
#include <stdint.h>

// Problem constants
#define NBATCH 4
#define SEQ    2048
#define DIM    1024

typedef __attribute__((ext_vector_type(8))) __bf16 bf16x8;
typedef __attribute__((ext_vector_type(4))) float  f32x4;

// Workspace layout (bytes)
#define OFF_XBF   (0ull)                         // 16 MiB
#define OFF_WBF   (16777216ull)                  //  6 MiB  [3072][1024] bf16
#define OFF_Q     (23068672ull)                  // 16 MiB (pre-scaled by 1/32)
#define OFF_K     (39845888ull)                  // 16 MiB
#define OFF_VT    (56623104ull)                  // 16 MiB  V^T per batch [DIM][SEQ]
#define OFF_SC    (73400320ull)                  // 32 MiB fp16 scores
#define OFF_P     (140509184ull)                 // 32 MiB bf16 probs

__device__ __forceinline__ uint16_t f2bf(float f) {
  uint32_t u = __float_as_uint(f);
  u = (u + 0x7fffu + ((u >> 16) & 1u)) >> 16;   // RTN-even
  return (uint16_t)u;
}

// ---------------- fused converts: X (blocks 0..8191), W (blocks 8192..11263) --
__global__ __launch_bounds__(256) void k_convert(const float* __restrict__ X,
                                                 const float* __restrict__ Wq,
                                                 const float* __restrict__ Wk,
                                                 const float* __restrict__ Wv,
                                                 uint16_t* __restrict__ Xbf,
                                                 uint16_t* __restrict__ Wbf) {
  int id = blockIdx.x;
  if (id < 8192) {
    int i = id * 256 + threadIdx.x;
    float4 v = ((const float4*)X)[i];
    ushort4 o;
    o.x = f2bf(v.x); o.y = f2bf(v.y); o.z = f2bf(v.z); o.w = f2bf(v.w);
    ((ushort4*)Xbf)[i] = o;
  } else {
    int j = id - 8192;                    // 0..3071
    int g = j >> 10;
    const float* W = (g == 0) ? Wq : (g == 1) ? Wk : Wv;
    float scale = (g == 0) ? 0.03125f : 1.0f;   // fold 1/sqrt(1024) into W_q
    int i = (j & 1023) * 256 + threadIdx.x;
    float4 v = ((const float4*)W)[i];
    ushort4 o;
    o.x = f2bf(v.x * scale); o.y = f2bf(v.y * scale);
    o.z = f2bf(v.z * scale); o.w = f2bf(v.w * scale);
    ((ushort4*)(Wbf + (size_t)g * 1048576))[i] = o;
  }
}

// ---------------- common helpers ----------------
// LDS rows are 64 bf16 = 128B; XOR swizzle byte ^= (row&7)<<4; inverse applied
// to the global SOURCE slot (global_load_lds writes linearly).

__device__ __forceinline__ void gll16(const void* g, void* l) {
  __builtin_amdgcn_global_load_lds((const __attribute__((address_space(1))) void*)g,
                                   (__attribute__((address_space(3))) void*)l, 16, 0, 0);
}

__device__ __forceinline__ bf16x8 frag_ld(const char* lds, int row, int kbyte) {
  int bo = row * 128 + kbyte;
  bo ^= (row & 7) << 4;
  return *(const bf16x8*)(lds + bo);
}

#define VM_WAIT8() asm volatile("s_waitcnt vmcnt(8)" ::: "memory")
#define VM_WAIT0() asm volatile("s_waitcnt vmcnt(0)" ::: "memory")
#define RAW_BAR()  asm volatile("s_barrier" ::: "memory")

// ============================================================================
// k_qkv: fused 8192x3072 GEMM, 256x256 tile, BK=64, 512 thr (8 waves, 2M x 4N),
// m201-quadrant 4-phase schedule, counted vmcnt(8) once per K-tile.
// LDS 128KB = 2 buf x {Ah0,Ah1,Bh0,Bh1} x 16KB ([128 rows][64 bf16] halves).
//
// Wave row assignment is INTERLEAVED so each quadrant reads exactly one half:
//   wave wm owns rows [wm*64, wm*64+64) of Ah0 (quadrant mh=0) and the same
//   rows of Ah1 (mh=1). Wave wn reads B-half (wn>>1), rows (wn&1)*64 + ...
// Free-list per K-tile t (all reads of a region complete before the barrier
// that precedes the overwrite of that region):
//   P1: [vmcnt(8); BAR] read av(Ah0) x8, bv01(Bh) x4; MFMA(mh0,nh0); BAR
//   P2: read bv23(Bh) x4; stage Ah0(t+2)   [Ah0(t) read only in P1]; MFMA(mh0,nh1); BAR
//   P3: read av(Ah1) x8; stage Bh0,Bh1(t+2)[bv reads only in P1,P2]; MFMA(mh1,nh0); BAR
//   P4: stage Ah1(t+2)                     [Ah1(t) read only in P3]; MFMA(mh1,nh1); BAR
// 8 stage-loads/thread per K-tile; entering P1(t) the outstanding set is
// exactly tile(t+1)'s 8 loads -> vmcnt(8) retires tile t. kt=15 -> vmcnt(0).
// ============================================================================

// stage one [128][64] half-tile with 512 threads: 2 loads/thread
__device__ __forceinline__ void stage_half(const uint16_t* __restrict__ g,
                                           int t, char* ldsH) {
#pragma unroll
  for (int c = 0; c < 2; ++c) {
    int L = c * 8192 + t * 16;
    int row = L >> 7;
    int slot = (t & 7) ^ (row & 7);
    gll16((const void*)(g + (size_t)row * DIM + slot * 8), (void*)(ldsH + L));
  }
}

template<int CUR>
__device__ __forceinline__ void qkv_ktile(char* lds, const uint16_t* __restrict__ A,
                                          const uint16_t* __restrict__ Bm,
                                          int t, int wm, int wn, int frow, int fk16,
                                          int kt, f32x4 (&acc)[8][4]) {
  char* base = lds + CUR * 65536;
  const char* Ah0 = base;
  const char* Ah1 = base + 16384;
  const char* Bh  = base + 32768 + (wn >> 1) * 16384;
  const int brow = (wn & 1) * 64;
  const bool stage_on = (kt <= 13);
  const int k2 = (kt + 2) * 64;                 // next-next tile column (<=15*64)

  bf16x8 av[4][2], bv01[2][2], bv23[2][2];

  // ---- P1: tile-t availability; read av(mh0) + bv01; MFMA (mh0,nh0) ----
  if (kt == 15) { VM_WAIT0(); } else { VM_WAIT8(); }
  RAW_BAR();
#pragma unroll
  for (int mq = 0; mq < 4; ++mq)
#pragma unroll
    for (int ki = 0; ki < 2; ++ki)
      av[mq][ki] = frag_ld(Ah0, wm * 64 + mq * 16 + frow, ki * 64 + fk16);
#pragma unroll
  for (int nq = 0; nq < 2; ++nq)
#pragma unroll
    for (int ki = 0; ki < 2; ++ki)
      bv01[nq][ki] = frag_ld(Bh, brow + nq * 16 + frow, ki * 64 + fk16);
  __builtin_amdgcn_s_setprio(1);
#pragma unroll
  for (int mq = 0; mq < 4; ++mq)
#pragma unroll
    for (int nq = 0; nq < 2; ++nq)
#pragma unroll
      for (int ki = 0; ki < 2; ++ki)
        acc[mq][nq] = __builtin_amdgcn_mfma_f32_16x16x32_bf16(av[mq][ki], bv01[nq][ki],
                                                              acc[mq][nq], 0, 0, 0);
  __builtin_amdgcn_s_setprio(0);
  RAW_BAR();

  // ---- P2: read bv23; stage Ah0(t+2); MFMA (mh0,nh1) ----
#pragma unroll
  for (int nq = 0; nq < 2; ++nq)
#pragma unroll
    for (int ki = 0; ki < 2; ++ki)
      bv23[nq][ki] = frag_ld(Bh, brow + 32 + nq * 16 + frow, ki * 64 + fk16);
  if (stage_on) stage_half(A + k2, t, base + 0);
  __builtin_amdgcn_s_setprio(1);
#pragma unroll
  for (int mq = 0; mq < 4; ++mq)
#pragma unroll
    for (int nq = 0; nq < 2; ++nq)
#pragma unroll
      for (int ki = 0; ki < 2; ++ki)
        acc[mq][2 + nq] = __builtin_amdgcn_mfma_f32_16x16x32_bf16(av[mq][ki], bv23[nq][ki],
                                                                  acc[mq][2 + nq], 0, 0, 0);
  __builtin_amdgcn_s_setprio(0);
  RAW_BAR();

  // ---- P3: read av(mh1); stage Bh0,Bh1(t+2); MFMA (mh1,nh0) ----
#pragma unroll
  for (int mq = 0; mq < 4; ++mq)
#pragma unroll
    for (int ki = 0; ki < 2; ++ki)
      av[mq][ki] = frag_ld(Ah1, wm * 64 + mq * 16 + frow, ki * 64 + fk16);
  if (stage_on) {
    stage_half(Bm + k2,             t, base + 32768);
    stage_half(Bm + 128 * DIM + k2, t, base + 49152);
  }
  __builtin_amdgcn_s_setprio(1);
#pragma unroll
  for (int mq = 0; mq < 4; ++mq)
#pragma unroll
    for (int nq = 0; nq < 2; ++nq)
#pragma unroll
      for (int ki = 0; ki < 2; ++ki)
        acc[4 + mq][nq] = __builtin_amdgcn_mfma_f32_16x16x32_bf16(av[mq][ki], bv01[nq][ki],
                                                                  acc[4 + mq][nq], 0, 0, 0);
  __builtin_amdgcn_s_setprio(0);
  RAW_BAR();

  // ---- P4: stage Ah1(t+2); MFMA (mh1,nh1) ----
  if (stage_on) stage_half(A + 128 * DIM + k2, t, base + 16384);
  __builtin_amdgcn_s_setprio(1);
#pragma unroll
  for (int mq = 0; mq < 4; ++mq)
#pragma unroll
    for (int nq = 0; nq < 2; ++nq)
#pragma unroll
      for (int ki = 0; ki < 2; ++ki)
        acc[4 + mq][2 + nq] = __builtin_amdgcn_mfma_f32_16x16x32_bf16(av[mq][ki], bv23[nq][ki],
                                                                      acc[4 + mq][2 + nq], 0, 0, 0);
  __builtin_amdgcn_s_setprio(0);
  RAW_BAR();
}

__global__ __launch_bounds__(512, 1) void k_qkv(const uint16_t* __restrict__ Xbf,
                                                const uint16_t* __restrict__ Wbf,
                                                uint16_t* __restrict__ Qb,
                                                uint16_t* __restrict__ Kb,
                                                uint16_t* __restrict__ Vt) {
  extern __shared__ char lds[];                 // 131072 bytes
  const int t = threadIdx.x;
  const int lane = t & 63;
  const int wid = t >> 6;
  const int wm = wid >> 2;                      // 0..1: rows wm*64 of EACH A-half
  const int wn = wid & 3;                       // 0..3: B-half wn>>1, sub (wn&1)*64
  const int frow = lane & 15;
  const int fk16 = (lane >> 4) * 16;

  // grid 384 = 32 mt x 12 nt, m-FASTEST (XCD m-residue keeps X slice L2-resident)
  int id = blockIdx.x;
  const int mt = id & 31, nt = id >> 5;
  const int m0 = mt * 256, n0 = nt * 256;
  const int g = n0 >> 10, ncol = n0 & 1023;

  const uint16_t* A  = Xbf + (size_t)m0 * DIM;
  const uint16_t* Bm = Wbf + (size_t)n0 * DIM;  // Wbf as [3072][1024]

  f32x4 acc[8][4];
#pragma unroll
  for (int i = 0; i < 8; ++i)
#pragma unroll
    for (int j = 0; j < 4; ++j) acc[i][j] = (f32x4){0.f, 0.f, 0.f, 0.f};

  // prologue: tile0 (buf0) then tile1 (buf1): 16 loads
  stage_half(A,                 t, lds + 0);
  stage_half(A  + 128 * DIM,    t, lds + 16384);
  stage_half(Bm,                t, lds + 32768);
  stage_half(Bm + 128 * DIM,    t, lds + 49152);
  stage_half(A  + 64,            t, lds + 65536 + 0);
  stage_half(A  + 128 * DIM + 64, t, lds + 65536 + 16384);
  stage_half(Bm + 64,            t, lds + 65536 + 32768);
  stage_half(Bm + 128 * DIM + 64, t, lds + 65536 + 49152);

#pragma unroll 1
  for (int t2 = 0; t2 < 16; t2 += 2) {
    qkv_ktile<0>(lds, A, Bm, t, wm, wn, frow, fk16, t2,     acc);
    qkv_ktile<1>(lds, A, Bm, t, wm, wn, frow, fk16, t2 + 1, acc);
  }

  // epilogue: acc[mf][nf]: row = m0 + (mf>>2)*128 + wm*64 + (mf&3)*16 + (lane>>4)*4 + r
  //           col = n0 + (wn>>1)*128 + (wn&1)*64 + nf*16 + (lane&15)
  const int rb0 = wm * 64 + (lane >> 4) * 4;
  const int cb0 = (wn >> 1) * 128 + (wn & 1) * 64 + (lane & 15);

  if (g < 2) {
    uint16_t* out = (g == 0) ? Qb : Kb;
#pragma unroll
    for (int mf = 0; mf < 8; ++mf)
#pragma unroll
      for (int nf = 0; nf < 4; ++nf) {
        int c = ncol + cb0 + nf * 16;
        int mrow = m0 + (mf >> 2) * 128 + rb0 + (mf & 3) * 16;
#pragma unroll
        for (int r = 0; r < 4; ++r)
          out[(size_t)(mrow + r) * DIM + c] = f2bf(acc[mf][nf][r]);
      }
  } else {
    const int b = m0 >> 11, sl = m0 & 2047;
#pragma unroll
    for (int mf = 0; mf < 8; ++mf)
#pragma unroll
      for (int nf = 0; nf < 4; ++nf) {
        int e = ncol + cb0 + nf * 16;
        int s = sl + (mf >> 2) * 128 + rb0 + (mf & 3) * 16;
        ushort4 o;
        o.x = f2bf(acc[mf][nf][0]); o.y = f2bf(acc[mf][nf][1]);
        o.z = f2bf(acc[mf][nf][2]); o.w = f2bf(acc[mf][nf][3]);
        *(ushort4*)(Vt + ((size_t)b * DIM + e) * SEQ + s) = o;
      }
  }
}

// ---------------- 128^2 GEMM core: 2-deep counted-vmcnt pipeline -------------
__device__ __forceinline__ void stage_tile(const uint16_t* __restrict__ g, int ld,
                                           int t, char* lds) {
#pragma unroll
  for (int c = 0; c < 4; ++c) {
    int L = c * 4096 + t * 16;
    int row = L >> 7;
    int slot = (t & 7) ^ (row & 7);
    gll16((const void*)(g + (size_t)row * ld + slot * 8), (void*)(lds + L));
  }
}

__device__ __forceinline__ void gemm_loop(const uint16_t* __restrict__ A, int lda,
                                          const uint16_t* __restrict__ Bm, int ldb,
                                          int ksteps, char* lds, f32x4 acc[4][4]) {
  char* lA0 = lds;          char* lA1 = lds + 16384;
  char* lB0 = lds + 32768;  char* lB1 = lds + 49152;
  const int t = threadIdx.x;
  const int lane = t & 63;
  const int wm = (t >> 6) & 1;
  const int wn = t >> 7;
  const int frow = lane & 15;
  const int fk16 = (lane >> 4) * 16;

  stage_tile(A,      lda, t, lA0); stage_tile(Bm,      ldb, t, lB0);
  if (ksteps > 1) { stage_tile(A + 64, lda, t, lA1); stage_tile(Bm + 64, ldb, t, lB1); }

  for (int kt = 0; kt < ksteps; ++kt) {
    if (kt == ksteps - 1) { VM_WAIT0(); } else { VM_WAIT8(); }
    RAW_BAR();
    const char* cA = (kt & 1) ? lA1 : lA0;
    const char* cB = (kt & 1) ? lB1 : lB0;
#pragma unroll
    for (int ki = 0; ki < 2; ++ki) {
      bf16x8 av[4], bv[4];
#pragma unroll
      for (int mi = 0; mi < 4; ++mi)
        av[mi] = frag_ld(cA, wm * 64 + mi * 16 + frow, ki * 64 + fk16);
#pragma unroll
      for (int ni = 0; ni < 4; ++ni)
        bv[ni] = frag_ld(cB, wn * 64 + ni * 16 + frow, ki * 64 + fk16);
      __builtin_amdgcn_s_setprio(1);
#pragma unroll
      for (int mi = 0; mi < 4; ++mi)
#pragma unroll
        for (int ni = 0; ni < 4; ++ni)
          acc[mi][ni] = __builtin_amdgcn_mfma_f32_16x16x32_bf16(av[mi], bv[ni],
                                                                acc[mi][ni], 0, 0, 0);
      __builtin_amdgcn_s_setprio(0);
    }
    RAW_BAR();
    if (kt + 2 < ksteps) {
      stage_tile(A  + (kt + 2) * 64, lda, t, (kt & 1) ? lA1 : lA0);
      stage_tile(Bm + (kt + 2) * 64, ldb, t, (kt & 1) ? lB1 : lB0);
    }
  }
}

// ---------------- causal scores: Sc = Q K^T (lower-tri 128x128 tiles, fp16) --
__global__ __launch_bounds__(256) void k_scores(const uint16_t* __restrict__ Qb,
                                                const uint16_t* __restrict__ Kb,
                                                __half* __restrict__ Sc) {
  __shared__ __align__(16) char lds[65536];
  int x = blockIdx.x;                 // 0..543
  int b = x / 136, tr = x % 136;
  int qt = 0;
  while ((qt + 1) * (qt + 2) / 2 <= tr) ++qt;
  int kt = tr - qt * (qt + 1) / 2;

  f32x4 acc[4][4];
#pragma unroll
  for (int i = 0; i < 4; ++i)
#pragma unroll
    for (int j = 0; j < 4; ++j) acc[i][j] = (f32x4){0.f, 0.f, 0.f, 0.f};

  const uint16_t* A = Qb + ((size_t)b * SEQ + qt * 128) * DIM;
  const uint16_t* Bm = Kb + ((size_t)b * SEQ + kt * 128) * DIM;
  gemm_loop(A, DIM, Bm, DIM, DIM / 64, lds, acc);

  const int lane = threadIdx.x & 63;
  const int wm = (threadIdx.x >> 6) & 1, wn = threadIdx.x >> 7;
  const int rbase = qt * 128 + wm * 64 + (lane >> 4) * 4;
  const int cbase = kt * 128 + wn * 64 + (lane & 15);
  __half* out = Sc + (size_t)b * SEQ * SEQ;
#pragma unroll
  for (int mi = 0; mi < 4; ++mi)
#pragma unroll
    for (int ni = 0; ni < 4; ++ni) {
      int c = cbase + ni * 16;
#pragma unroll
      for (int r = 0; r < 4; ++r)
        out[(size_t)(rbase + mi * 16 + r) * SEQ + c] = __float2half(acc[mi][ni][r]);
    }
}

// ---------------- row softmax: one WAVE per row, fp16 row in registers -------
struct h4 { __half2 a, b; };          // 8 bytes = 4 halves

__global__ __launch_bounds__(256) void k_softmax(const __half* __restrict__ Sc,
                                                 uint16_t* __restrict__ P) {
  int gid = blockIdx.x * 4 + (threadIdx.x >> 6);
  int lane = threadIdx.x & 63;
  int b = gid >> 11, q = gid & 2047;
  const __half* srow = Sc + ((size_t)b * SEQ + q) * SEQ;
  uint16_t* prow = P + ((size_t)b * SEQ + q) * SEQ;
  int nv = q + 1;
  int kpad = ((q >> 7) + 1) << 7;     // PV reads exactly [0, kpad)
  int niter = (kpad + 255) >> 8;      // 256 halves per wave-iter

  float4 v[8];
  const h4* src = (const h4*)srow;
#pragma unroll
  for (int i = 0; i < 8; ++i) {
    if (i < niter) {
      int idx = lane + (i << 6);
      h4 raw = src[idx];
      float2 fa = __half22float2(raw.a), fb = __half22float2(raw.b);
      int k0 = idx << 2;
      float4 x;
      x.x = (k0 + 0 < nv) ? fa.x : -1e38f;
      x.y = (k0 + 1 < nv) ? fa.y : -1e38f;
      x.z = (k0 + 2 < nv) ? fb.x : -1e38f;
      x.w = (k0 + 3 < nv) ? fb.y : -1e38f;
      v[i] = x;
    } else {
      v[i] = make_float4(-1e38f, -1e38f, -1e38f, -1e38f);
    }
  }
  float m = -1e38f;
#pragma unroll
  for (int i = 0; i < 8; ++i)
    m = fmaxf(m, fmaxf(fmaxf(v[i].x, v[i].y), fmaxf(v[i].z, v[i].w)));
#pragma unroll
  for (int o = 32; o > 0; o >>= 1) m = fmaxf(m, __shfl_xor(m, o));

  float s = 0.f;
#pragma unroll
  for (int i = 0; i < 8; ++i) {
    v[i].x = __expf(v[i].x - m); v[i].y = __expf(v[i].y - m);
    v[i].z = __expf(v[i].z - m); v[i].w = __expf(v[i].w - m);
    s += v[i].x + v[i].y + v[i].z + v[i].w;
  }
#pragma unroll
  for (int o = 32; o > 0; o >>= 1) s += __shfl_xor(s, o);
  float inv = 1.0f / s;

  ushort4* dst = (ushort4*)prow;
#pragma unroll
  for (int i = 0; i < 8; ++i) {
    if (i < niter) {
      int idx = lane + (i << 6);
      if ((idx << 2) < kpad) {
        ushort4 o;
        o.x = f2bf(v[i].x * inv); o.y = f2bf(v[i].y * inv);
        o.z = f2bf(v[i].z * inv); o.w = f2bf(v[i].w * inv);
        dst[idx] = o;
      }
    }
  }
}

// ---------------- PV: O = P V  (A=P, B=Vt rows=e, cols=k) ----------------
// Block remap pairs complementary qt on the same CU (blocks x and x+256 land on
// the same CU): qt(x) + qt(x+256) = 15 -> uniform 34 K-steps per CU (the old
// mapping put two SAME-qt blocks together: critical path 2x full-K ~ 40us).
__global__ __launch_bounds__(256) void k_pv(const uint16_t* __restrict__ P,
                                            const uint16_t* __restrict__ Vt,
                                            float* __restrict__ O) {
  __shared__ __align__(16) char lds[65536];
  int x = blockIdx.x;                 // 512
  int idx = x & 255, half = x >> 8;
  int qt = half ? (idx >> 4) : 15 - (idx >> 4);
  int et = idx & 7;
  int b  = ((idx >> 3) & 1) | (half << 1);

  f32x4 acc[4][4];
#pragma unroll
  for (int i = 0; i < 4; ++i)
#pragma unroll
    for (int j = 0; j < 4; ++j) acc[i][j] = (f32x4){0.f, 0.f, 0.f, 0.f};

  const uint16_t* A = P + (size_t)b * SEQ * SEQ + (size_t)qt * 128 * SEQ;
  const uint16_t* Bm = Vt + (size_t)b * DIM * SEQ + (size_t)et * 128 * SEQ;
  gemm_loop(A, SEQ, Bm, SEQ, (qt + 1) * 2, lds, acc);

  const int lane = threadIdx.x & 63;
  const int wm = (threadIdx.x >> 6) & 1, wn = threadIdx.x >> 7;
  const int rbase = qt * 128 + wm * 64 + (lane >> 4) * 4;
  const int cbase = et * 128 + wn * 64 + (lane & 15);
  float* out = O + (size_t)b * SEQ * DIM;
#pragma unroll
  for (int mi = 0; mi < 4; ++mi)
#pragma unroll
    for (int ni = 0; ni < 4; ++ni) {
      int c = cbase + ni * 16;
#pragma unroll
      for (int r = 0; r < 4; ++r)
        out[(size_t)(rbase + mi * 16 + r) * DIM + c] = acc[mi][ni][r];
    }
}

extern "C" void kernel_launch(void* const* d_in, const int* in_sizes, int n_in,
                              void* d_out, int out_size, void* d_ws, size_t ws_size,
                              hipStream_t stream) {
  const float* X  = (const float*)d_in[0];
  const float* Wq = (const float*)d_in[1];
  const float* Wk = (const float*)d_in[2];
  const float* Wv = (const float*)d_in[3];
  char* ws = (char*)d_ws;
  uint16_t* Xbf = (uint16_t*)(ws + OFF_XBF);
  uint16_t* Wbf = (uint16_t*)(ws + OFF_WBF);
  uint16_t* Qb  = (uint16_t*)(ws + OFF_Q);
  uint16_t* Kb  = (uint16_t*)(ws + OFF_K);
  uint16_t* Vt  = (uint16_t*)(ws + OFF_VT);
  __half*   Sc  = (__half*)(ws + OFF_SC);
  uint16_t* P   = (uint16_t*)(ws + OFF_P);
  float*    O   = (float*)d_out;

  k_convert<<<11264, 256, 0, stream>>>(X, Wq, Wk, Wv, Xbf, Wbf);
  k_qkv<<<384, 512, 131072, stream>>>(Xbf, Wbf, Qb, Kb, Vt);
  k_scores<<<544, 256, 0, stream>>>(Qb, Kb, Sc);
  k_softmax<<<2048, 256, 0, stream>>>(Sc, P);
  k_pv<<<512, 256, 0, stream>>>(P, Vt, O);
}

// Round 8
// 144.813 us; speedup vs baseline: 1.1444x; 1.1174x over previous
//
#include <hip/hip_runtime.h>
#include <hip/hip_bf16.h>
#include <hip/hip_fp16.h>
#include <stdint.h>

// Problem constants
#define NBATCH 4
#define SEQ    2048
#define DIM    1024

typedef __attribute__((ext_vector_type(8))) __bf16 bf16x8;
typedef __attribute__((ext_vector_type(4))) float  f32x4;

// Workspace layout (bytes)
#define OFF_XBF   (0ull)                         // 16 MiB
#define OFF_WBF   (16777216ull)                  //  6 MiB  [3072][1024] bf16
#define OFF_Q     (23068672ull)                  // 16 MiB (pre-scaled by 1/32)
#define OFF_K     (39845888ull)                  // 16 MiB
#define OFF_VT    (56623104ull)                  // 16 MiB  V^T per batch [DIM][SEQ]
#define OFF_SC    (73400320ull)                  // 32 MiB fp16 scores
#define OFF_P     (140509184ull)                 // 32 MiB bf16 probs

__device__ __forceinline__ uint16_t f2bf(float f) {
  uint32_t u = __float_as_uint(f);
  u = (u + 0x7fffu + ((u >> 16) & 1u)) >> 16;   // RTN-even
  return (uint16_t)u;
}

// ---------------- fused converts: X (blocks 0..8191), W (blocks 8192..11263) --
__global__ __launch_bounds__(256) void k_convert(const float* __restrict__ X,
                                                 const float* __restrict__ Wq,
                                                 const float* __restrict__ Wk,
                                                 const float* __restrict__ Wv,
                                                 uint16_t* __restrict__ Xbf,
                                                 uint16_t* __restrict__ Wbf) {
  int id = blockIdx.x;
  if (id < 8192) {
    int i = id * 256 + threadIdx.x;
    float4 v = ((const float4*)X)[i];
    ushort4 o;
    o.x = f2bf(v.x); o.y = f2bf(v.y); o.z = f2bf(v.z); o.w = f2bf(v.w);
    ((ushort4*)Xbf)[i] = o;
  } else {
    int j = id - 8192;                    // 0..3071
    int g = j >> 10;
    const float* W = (g == 0) ? Wq : (g == 1) ? Wk : Wv;
    float scale = (g == 0) ? 0.03125f : 1.0f;   // fold 1/sqrt(1024) into W_q
    int i = (j & 1023) * 256 + threadIdx.x;
    float4 v = ((const float4*)W)[i];
    ushort4 o;
    o.x = f2bf(v.x * scale); o.y = f2bf(v.y * scale);
    o.z = f2bf(v.z * scale); o.w = f2bf(v.w * scale);
    ((ushort4*)(Wbf + (size_t)g * 1048576))[i] = o;
  }
}

// ---------------- common helpers ----------------
// LDS rows are 64 bf16 = 128B; XOR swizzle byte ^= (row&7)<<4; inverse applied
// to the global SOURCE slot (global_load_lds writes linearly).

__device__ __forceinline__ void gll16(const void* g, void* l) {
  __builtin_amdgcn_global_load_lds((const __attribute__((address_space(1))) void*)g,
                                   (__attribute__((address_space(3))) void*)l, 16, 0, 0);
}

__device__ __forceinline__ bf16x8 frag_ld(const char* lds, int row, int kbyte) {
  int bo = row * 128 + kbyte;
  bo ^= (row & 7) << 4;
  return *(const bf16x8*)(lds + bo);
}

#define VM_WAIT8() asm volatile("s_waitcnt vmcnt(8)" ::: "memory")
#define VM_WAIT6() asm volatile("s_waitcnt vmcnt(6)" ::: "memory")
#define VM_WAIT0() asm volatile("s_waitcnt vmcnt(0)" ::: "memory")
#define RAW_BAR()  asm volatile("s_barrier" ::: "memory")

// ---------------- 128^2 GEMM core: 2-deep counted-vmcnt pipeline -------------
// Ledger (8 loads/thread per tile = A4 + B4, uniform issue order across threads):
//   prologue: stage(0), stage(1)                      -> 16 loads outstanding
//   tile t entry: vmcnt(8) retires exactly stage(t); barrier => LDS visible
//   post-compute barrier => all reads of buf[t&1] done; then stage(t+2) -> WAR safe
__device__ __forceinline__ void stage_tile(const uint16_t* __restrict__ g, int ld,
                                           int t, char* lds) {
#pragma unroll
  for (int c = 0; c < 4; ++c) {
    int L = c * 4096 + t * 16;
    int row = L >> 7;
    int slot = (t & 7) ^ (row & 7);
    gll16((const void*)(g + (size_t)row * ld + slot * 8), (void*)(lds + L));
  }
}

__device__ __forceinline__ void gemm_loop(const uint16_t* __restrict__ A, int lda,
                                          const uint16_t* __restrict__ Bm, int ldb,
                                          int ksteps, char* lds, f32x4 acc[4][4]) {
  char* lA0 = lds;          char* lA1 = lds + 16384;
  char* lB0 = lds + 32768;  char* lB1 = lds + 49152;
  const int t = threadIdx.x;
  const int lane = t & 63;
  const int wm = (t >> 6) & 1;
  const int wn = t >> 7;
  const int frow = lane & 15;
  const int fk16 = (lane >> 4) * 16;

  stage_tile(A,      lda, t, lA0); stage_tile(Bm,      ldb, t, lB0);
  if (ksteps > 1) { stage_tile(A + 64, lda, t, lA1); stage_tile(Bm + 64, ldb, t, lB1); }

  for (int kt = 0; kt < ksteps; ++kt) {
    if (kt == ksteps - 1) { VM_WAIT0(); } else { VM_WAIT8(); }
    RAW_BAR();
    const char* cA = (kt & 1) ? lA1 : lA0;
    const char* cB = (kt & 1) ? lB1 : lB0;
#pragma unroll
    for (int ki = 0; ki < 2; ++ki) {
      bf16x8 av[4], bv[4];
#pragma unroll
      for (int mi = 0; mi < 4; ++mi)
        av[mi] = frag_ld(cA, wm * 64 + mi * 16 + frow, ki * 64 + fk16);
#pragma unroll
      for (int ni = 0; ni < 4; ++ni)
        bv[ni] = frag_ld(cB, wn * 64 + ni * 16 + frow, ki * 64 + fk16);
      __builtin_amdgcn_s_setprio(1);
#pragma unroll
      for (int mi = 0; mi < 4; ++mi)
#pragma unroll
        for (int ni = 0; ni < 4; ++ni)
          acc[mi][ni] = __builtin_amdgcn_mfma_f32_16x16x32_bf16(av[mi], bv[ni],
                                                                acc[mi][ni], 0, 0, 0);
      __builtin_amdgcn_s_setprio(0);
    }
    RAW_BAR();
    if (kt + 2 < ksteps) {
      stage_tile(A  + (kt + 2) * 64, lda, t, (kt & 1) ? lA1 : lA0);
      stage_tile(Bm + (kt + 2) * 64, ldb, t, (kt & 1) ? lB1 : lB0);
    }
  }
}

// ---------------- 128x64 half-tile GEMM core (scores): vmcnt(6), 48KB LDS ----
// B tile is 64x64 (8KB): 2 loads/thread; A tile 128x64 (16KB): 4 loads/thread.
// Same ledger as gemm_loop with 6 loads/K-tile: prologue 12 outstanding,
// entry vmcnt(6) retires exactly tile t's 6.
__device__ __forceinline__ void stage_btile(const uint16_t* __restrict__ g, int ld,
                                            int t, char* lds) {
#pragma unroll
  for (int c = 0; c < 2; ++c) {
    int L = c * 4096 + t * 16;
    int row = L >> 7;
    int slot = (t & 7) ^ (row & 7);
    gll16((const void*)(g + (size_t)row * ld + slot * 8), (void*)(lds + L));
  }
}

__device__ __forceinline__ void gemm_loop_h(const uint16_t* __restrict__ A, int lda,
                                            const uint16_t* __restrict__ Bm, int ldb,
                                            int ksteps, char* lds, f32x4 acc[4][2]) {
  char* lA0 = lds;          char* lA1 = lds + 16384;
  char* lB0 = lds + 32768;  char* lB1 = lds + 40960;
  const int t = threadIdx.x;
  const int lane = t & 63;
  const int wm = (t >> 6) & 1;                  // 64-row strip
  const int wn = t >> 7;                        // 32-col strip (0..1)
  const int frow = lane & 15;
  const int fk16 = (lane >> 4) * 16;

  stage_tile(A, lda, t, lA0); stage_btile(Bm, ldb, t, lB0);
  if (ksteps > 1) { stage_tile(A + 64, lda, t, lA1); stage_btile(Bm + 64, ldb, t, lB1); }

  for (int kt = 0; kt < ksteps; ++kt) {
    if (kt == ksteps - 1) { VM_WAIT0(); } else { VM_WAIT6(); }
    RAW_BAR();
    const char* cA = (kt & 1) ? lA1 : lA0;
    const char* cB = (kt & 1) ? lB1 : lB0;
#pragma unroll
    for (int ki = 0; ki < 2; ++ki) {
      bf16x8 av[4], bv[2];
#pragma unroll
      for (int mi = 0; mi < 4; ++mi)
        av[mi] = frag_ld(cA, wm * 64 + mi * 16 + frow, ki * 64 + fk16);
#pragma unroll
      for (int ni = 0; ni < 2; ++ni)
        bv[ni] = frag_ld(cB, wn * 32 + ni * 16 + frow, ki * 64 + fk16);
      __builtin_amdgcn_s_setprio(1);
#pragma unroll
      for (int mi = 0; mi < 4; ++mi)
#pragma unroll
        for (int ni = 0; ni < 2; ++ni)
          acc[mi][ni] = __builtin_amdgcn_mfma_f32_16x16x32_bf16(av[mi], bv[ni],
                                                                acc[mi][ni], 0, 0, 0);
      __builtin_amdgcn_s_setprio(0);
    }
    RAW_BAR();
    if (kt + 2 < ksteps) {
      stage_tile (A  + (kt + 2) * 64, lda, t, (kt & 1) ? lA1 : lA0);
      stage_btile(Bm + (kt + 2) * 64, ldb, t, (kt & 1) ? lB1 : lB0);
    }
  }
}

// ---------------- QKV projection: fused 8192x3072, 128^2 tiles, 2 blocks/CU --
// Grid 1536 = 64 m x 24 n, m-FASTEST, no swizzle: id = mt + 64*nt.
// Round-robin dispatch => id mod 8 = XCD, and 64*nt mod 8 == 0, so each XCD
// only ever touches m-tiles with mt mod 8 == xcd: 2MB X-slice + ~2MB W in-flight
// stays L2-resident (proven: FETCH 47MB in R5 vs 200MB with swizzle in R4).
__global__ __launch_bounds__(256) void k_qkv(const uint16_t* __restrict__ Xbf,
                                             const uint16_t* __restrict__ Wbf,
                                             uint16_t* __restrict__ Qb,
                                             uint16_t* __restrict__ Kb,
                                             uint16_t* __restrict__ Vt) {
  __shared__ __align__(16) char lds[65536];
  int id = blockIdx.x;
  const int mt = id & 63, nt = id >> 6;
  const int m0 = mt * 128, n0 = nt * 128;
  const int g = n0 >> 10, ncol = n0 & 1023;

  f32x4 acc[4][4];
#pragma unroll
  for (int i = 0; i < 4; ++i)
#pragma unroll
    for (int j = 0; j < 4; ++j) acc[i][j] = (f32x4){0.f, 0.f, 0.f, 0.f};

  const uint16_t* A  = Xbf + (size_t)m0 * DIM;
  const uint16_t* Bm = Wbf + (size_t)n0 * DIM;  // Wbf as [3072][1024]
  gemm_loop(A, DIM, Bm, DIM, DIM / 64, lds, acc);

  const int lane = threadIdx.x & 63;
  const int wm = (threadIdx.x >> 6) & 1, wn = threadIdx.x >> 7;
  const int rbase = wm * 64 + (lane >> 4) * 4;  // C row = (lane>>4)*4 + reg
  const int cbase = wn * 64 + (lane & 15);      // C col = lane&15

  if (g < 2) {
    uint16_t* out = (g == 0) ? Qb : Kb;
#pragma unroll
    for (int mi = 0; mi < 4; ++mi)
#pragma unroll
      for (int ni = 0; ni < 4; ++ni) {
        int c = ncol + cbase + ni * 16;
#pragma unroll
        for (int r = 0; r < 4; ++r) {
          int m = m0 + rbase + mi * 16 + r;
          out[(size_t)m * DIM + c] = f2bf(acc[mi][ni][r]);
        }
      }
  } else {
    // write V transposed: Vt[b][e][s]
    const int b = m0 >> 11, sl = m0 & 2047;
#pragma unroll
    for (int mi = 0; mi < 4; ++mi)
#pragma unroll
      for (int ni = 0; ni < 4; ++ni) {
        int e = ncol + cbase + ni * 16;
        int s = sl + rbase + mi * 16;
        ushort4 o;
        o.x = f2bf(acc[mi][ni][0]); o.y = f2bf(acc[mi][ni][1]);
        o.z = f2bf(acc[mi][ni][2]); o.w = f2bf(acc[mi][ni][3]);
        *(ushort4*)(Vt + ((size_t)b * DIM + e) * SEQ + s) = o;
      }
  }
}

// ---------------- causal scores: Sc = Q K^T, 128x64 half-tile jobs, fp16 -----
// 1088 jobs = 4 batches x 136 lower-tri tiles x 2 column-halves; 48KB LDS ->
// 3 blocks/CU (768 slots). Two rounds of HALF-length jobs ~ 1.1x one full
// round, vs the old 544-on-512 layout's 2 full rounds.
__global__ __launch_bounds__(256) void k_scores(const uint16_t* __restrict__ Qb,
                                                const uint16_t* __restrict__ Kb,
                                                __half* __restrict__ Sc) {
  __shared__ __align__(16) char lds[49152];
  int j = blockIdx.x;                 // 0..1087
  int b = j / 272, r = j % 272;
  int tr = r >> 1, nh = r & 1;
  int qt = 0;
  while ((qt + 1) * (qt + 2) / 2 <= tr) ++qt;
  int kt = tr - qt * (qt + 1) / 2;

  f32x4 acc[4][2];
#pragma unroll
  for (int i = 0; i < 4; ++i)
#pragma unroll
    for (int jj = 0; jj < 2; ++jj) acc[i][jj] = (f32x4){0.f, 0.f, 0.f, 0.f};

  const uint16_t* A  = Qb + ((size_t)b * SEQ + qt * 128) * DIM;
  const uint16_t* Bm = Kb + ((size_t)b * SEQ + kt * 128 + nh * 64) * DIM;
  gemm_loop_h(A, DIM, Bm, DIM, DIM / 64, lds, acc);

  const int lane = threadIdx.x & 63;
  const int wm = (threadIdx.x >> 6) & 1, wn = threadIdx.x >> 7;
  const int rbase = qt * 128 + wm * 64 + (lane >> 4) * 4;
  const int cbase = kt * 128 + nh * 64 + wn * 32 + (lane & 15);
  __half* out = Sc + (size_t)b * SEQ * SEQ;
#pragma unroll
  for (int mi = 0; mi < 4; ++mi)
#pragma unroll
    for (int ni = 0; ni < 2; ++ni) {
      int c = cbase + ni * 16;
#pragma unroll
      for (int r = 0; r < 4; ++r)
        out[(size_t)(rbase + mi * 16 + r) * SEQ + c] = __float2half(acc[mi][ni][r]);
    }
}

// ---------------- row softmax: one WAVE per row, fp16 row in registers -------
struct h4 { __half2 a, b; };          // 8 bytes = 4 halves

__global__ __launch_bounds__(256) void k_softmax(const __half* __restrict__ Sc,
                                                 uint16_t* __restrict__ P) {
  int gid = blockIdx.x * 4 + (threadIdx.x >> 6);
  int lane = threadIdx.x & 63;
  int b = gid >> 11, q = gid & 2047;
  const __half* srow = Sc + ((size_t)b * SEQ + q) * SEQ;
  uint16_t* prow = P + ((size_t)b * SEQ + q) * SEQ;
  int nv = q + 1;
  int kpad = ((q >> 7) + 1) << 7;     // PV reads exactly [0, kpad)
  int niter = (kpad + 255) >> 8;      // 256 halves per wave-iter

  float4 v[8];
  const h4* src = (const h4*)srow;
#pragma unroll
  for (int i = 0; i < 8; ++i) {
    if (i < niter) {
      int idx = lane + (i << 6);
      h4 raw = src[idx];
      float2 fa = __half22float2(raw.a), fb = __half22float2(raw.b);
      int k0 = idx << 2;
      float4 x;
      x.x = (k0 + 0 < nv) ? fa.x : -1e38f;
      x.y = (k0 + 1 < nv) ? fa.y : -1e38f;
      x.z = (k0 + 2 < nv) ? fb.x : -1e38f;
      x.w = (k0 + 3 < nv) ? fb.y : -1e38f;
      v[i] = x;
    } else {
      v[i] = make_float4(-1e38f, -1e38f, -1e38f, -1e38f);
    }
  }
  float m = -1e38f;
#pragma unroll
  for (int i = 0; i < 8; ++i)
    m = fmaxf(m, fmaxf(fmaxf(v[i].x, v[i].y), fmaxf(v[i].z, v[i].w)));
#pragma unroll
  for (int o = 32; o > 0; o >>= 1) m = fmaxf(m, __shfl_xor(m, o));

  float s = 0.f;
#pragma unroll
  for (int i = 0; i < 8; ++i) {
    v[i].x = __expf(v[i].x - m); v[i].y = __expf(v[i].y - m);
    v[i].z = __expf(v[i].z - m); v[i].w = __expf(v[i].w - m);
    s += v[i].x + v[i].y + v[i].z + v[i].w;
  }
#pragma unroll
  for (int o = 32; o > 0; o >>= 1) s += __shfl_xor(s, o);
  float inv = 1.0f / s;

  ushort4* dst = (ushort4*)prow;
#pragma unroll
  for (int i = 0; i < 8; ++i) {
    if (i < niter) {
      int idx = lane + (i << 6);
      if ((idx << 2) < kpad) {
        ushort4 o;
        o.x = f2bf(v[i].x * inv); o.y = f2bf(v[i].y * inv);
        o.z = f2bf(v[i].z * inv); o.w = f2bf(v[i].w * inv);
        dst[idx] = o;
      }
    }
  }
}

// ---------------- PV: O = P V  (A=P, B=Vt rows=e, cols=k) ----------------
// Block remap pairs complementary qt on the same CU (blocks x and x+256 land on
// the same CU): qt(x) + qt(x+256) = 15 -> uniform 34 K-steps per CU. This was
// the +10us of R7 (non-qkv part 99.1 -> 89.1 us).
__global__ __launch_bounds__(256) void k_pv(const uint16_t* __restrict__ P,
                                            const uint16_t* __restrict__ Vt,
                                            float* __restrict__ O) {
  __shared__ __align__(16) char lds[65536];
  int x = blockIdx.x;                 // 512
  int idx = x & 255, half = x >> 8;
  int qt = half ? (idx >> 4) : 15 - (idx >> 4);
  int et = idx & 7;
  int b  = ((idx >> 3) & 1) | (half << 1);

  f32x4 acc[4][4];
#pragma unroll
  for (int i = 0; i < 4; ++i)
#pragma unroll
    for (int j = 0; j < 4; ++j) acc[i][j] = (f32x4){0.f, 0.f, 0.f, 0.f};

  const uint16_t* A = P + (size_t)b * SEQ * SEQ + (size_t)qt * 128 * SEQ;
  const uint16_t* Bm = Vt + (size_t)b * DIM * SEQ + (size_t)et * 128 * SEQ;
  gemm_loop(A, SEQ, Bm, SEQ, (qt + 1) * 2, lds, acc);

  const int lane = threadIdx.x & 63;
  const int wm = (threadIdx.x >> 6) & 1, wn = threadIdx.x >> 7;
  const int rbase = qt * 128 + wm * 64 + (lane >> 4) * 4;
  const int cbase = et * 128 + wn * 64 + (lane & 15);
  float* out = O + (size_t)b * SEQ * DIM;
#pragma unroll
  for (int mi = 0; mi < 4; ++mi)
#pragma unroll
    for (int ni = 0; ni < 4; ++ni) {
      int c = cbase + ni * 16;
#pragma unroll
      for (int r = 0; r < 4; ++r)
        out[(size_t)(rbase + mi * 16 + r) * DIM + c] = acc[mi][ni][r];
    }
}

extern "C" void kernel_launch(void* const* d_in, const int* in_sizes, int n_in,
                              void* d_out, int out_size, void* d_ws, size_t ws_size,
                              hipStream_t stream) {
  const float* X  = (const float*)d_in[0];
  const float* Wq = (const float*)d_in[1];
  const float* Wk = (const float*)d_in[2];
  const float* Wv = (const float*)d_in[3];
  char* ws = (char*)d_ws;
  uint16_t* Xbf = (uint16_t*)(ws + OFF_XBF);
  uint16_t* Wbf = (uint16_t*)(ws + OFF_WBF);
  uint16_t* Qb  = (uint16_t*)(ws + OFF_Q);
  uint16_t* Kb  = (uint16_t*)(ws + OFF_K);
  uint16_t* Vt  = (uint16_t*)(ws + OFF_VT);
  __half*   Sc  = (__half*)(ws + OFF_SC);
  uint16_t* P   = (uint16_t*)(ws + OFF_P);
  float*    O   = (float*)d_out;

  k_convert<<<11264, 256, 0, stream>>>(X, Wq, Wk, Wv, Xbf, Wbf);
  k_qkv<<<1536, 256, 0, stream>>>(Xbf, Wbf, Qb, Kb, Vt);
  k_scores<<<1088, 256, 0, stream>>>(Qb, Kb, Sc);
  k_softmax<<<2048, 256, 0, stream>>>(Sc, P);
  k_pv<<<512, 256, 0, stream>>>(P, Vt, O);
}

// Round 9
// 143.071 us; speedup vs baseline: 1.1583x; 1.0122x over previous
//
#include <hip/hip_runtime.h>
#include <hip/hip_bf16.h>
#include <hip/hip_fp16.h>
#include <stdint.h>

// Problem constants
#define NBATCH 4
#define SEQ    2048
#define DIM    1024

typedef __attribute__((ext_vector_type(8))) __bf16 bf16x8;
typedef __attribute__((ext_vector_type(4))) float  f32x4;

// Workspace layout (bytes)
#define OFF_XBF   (0ull)                         // 16 MiB
#define OFF_WBF   (16777216ull)                  //  6 MiB  [3072][1024] bf16
#define OFF_Q     (23068672ull)                  // 16 MiB (pre-scaled by 1/32)
#define OFF_K     (39845888ull)                  // 16 MiB
#define OFF_VT    (56623104ull)                  // 16 MiB  V^T per batch [DIM][SEQ]
#define OFF_SC    (73400320ull)                  // 32 MiB fp16 scores
#define OFF_P     (140509184ull)                 // 32 MiB bf16 probs

__device__ __forceinline__ uint16_t f2bf(float f) {
  uint32_t u = __float_as_uint(f);
  u = (u + 0x7fffu + ((u >> 16) & 1u)) >> 16;   // RTN-even
  return (uint16_t)u;
}

// ---------------- fused converts: X (blocks 0..8191), W (blocks 8192..11263) --
__global__ __launch_bounds__(256) void k_convert(const float* __restrict__ X,
                                                 const float* __restrict__ Wq,
                                                 const float* __restrict__ Wk,
                                                 const float* __restrict__ Wv,
                                                 uint16_t* __restrict__ Xbf,
                                                 uint16_t* __restrict__ Wbf) {
  int id = blockIdx.x;
  if (id < 8192) {
    int i = id * 256 + threadIdx.x;
    float4 v = ((const float4*)X)[i];
    ushort4 o;
    o.x = f2bf(v.x); o.y = f2bf(v.y); o.z = f2bf(v.z); o.w = f2bf(v.w);
    ((ushort4*)Xbf)[i] = o;
  } else {
    int j = id - 8192;                    // 0..3071
    int g = j >> 10;
    const float* W = (g == 0) ? Wq : (g == 1) ? Wk : Wv;
    float scale = (g == 0) ? 0.03125f : 1.0f;   // fold 1/sqrt(1024) into W_q
    int i = (j & 1023) * 256 + threadIdx.x;
    float4 v = ((const float4*)W)[i];
    ushort4 o;
    o.x = f2bf(v.x * scale); o.y = f2bf(v.y * scale);
    o.z = f2bf(v.z * scale); o.w = f2bf(v.w * scale);
    ((ushort4*)(Wbf + (size_t)g * 1048576))[i] = o;
  }
}

// ---------------- common helpers ----------------
// LDS rows are 64 bf16 = 128B; XOR swizzle byte ^= (row&7)<<4; inverse applied
// to the global SOURCE slot (global_load_lds writes linearly).

__device__ __forceinline__ void gll16(const void* g, void* l) {
  __builtin_amdgcn_global_load_lds((const __attribute__((address_space(1))) void*)g,
                                   (__attribute__((address_space(3))) void*)l, 16, 0, 0);
}

__device__ __forceinline__ bf16x8 frag_ld(const char* lds, int row, int kbyte) {
  int bo = row * 128 + kbyte;
  bo ^= (row & 7) << 4;
  return *(const bf16x8*)(lds + bo);
}

#define VM_WAIT8() asm volatile("s_waitcnt vmcnt(8)" ::: "memory")
#define VM_WAIT6() asm volatile("s_waitcnt vmcnt(6)" ::: "memory")
#define VM_WAIT0() asm volatile("s_waitcnt vmcnt(0)" ::: "memory")
#define RAW_BAR()  asm volatile("s_barrier" ::: "memory")

// ---------------- 128^2 GEMM core: 2-deep counted-vmcnt pipeline -------------
// Ledger (8 loads/thread per tile = A4 + B4, uniform issue order across threads):
//   prologue: stage(0), stage(1)                      -> 16 loads outstanding
//   tile t entry: vmcnt(8) retires exactly stage(t); barrier => LDS visible
//   post-compute barrier => all reads of buf[t&1] done; then stage(t+2) -> WAR safe
__device__ __forceinline__ void stage_tile(const uint16_t* __restrict__ g, int ld,
                                           int t, char* lds) {
#pragma unroll
  for (int c = 0; c < 4; ++c) {
    int L = c * 4096 + t * 16;
    int row = L >> 7;
    int slot = (t & 7) ^ (row & 7);
    gll16((const void*)(g + (size_t)row * ld + slot * 8), (void*)(lds + L));
  }
}

__device__ __forceinline__ void gemm_loop(const uint16_t* __restrict__ A, int lda,
                                          const uint16_t* __restrict__ Bm, int ldb,
                                          int ksteps, char* lds, f32x4 acc[4][4]) {
  char* lA0 = lds;          char* lA1 = lds + 16384;
  char* lB0 = lds + 32768;  char* lB1 = lds + 49152;
  const int t = threadIdx.x;
  const int lane = t & 63;
  const int wm = (t >> 6) & 1;
  const int wn = t >> 7;
  const int frow = lane & 15;
  const int fk16 = (lane >> 4) * 16;

  stage_tile(A,      lda, t, lA0); stage_tile(Bm,      ldb, t, lB0);
  if (ksteps > 1) { stage_tile(A + 64, lda, t, lA1); stage_tile(Bm + 64, ldb, t, lB1); }

  for (int kt = 0; kt < ksteps; ++kt) {
    if (kt == ksteps - 1) { VM_WAIT0(); } else { VM_WAIT8(); }
    RAW_BAR();
    const char* cA = (kt & 1) ? lA1 : lA0;
    const char* cB = (kt & 1) ? lB1 : lB0;
#pragma unroll
    for (int ki = 0; ki < 2; ++ki) {
      bf16x8 av[4], bv[4];
#pragma unroll
      for (int mi = 0; mi < 4; ++mi)
        av[mi] = frag_ld(cA, wm * 64 + mi * 16 + frow, ki * 64 + fk16);
#pragma unroll
      for (int ni = 0; ni < 4; ++ni)
        bv[ni] = frag_ld(cB, wn * 64 + ni * 16 + frow, ki * 64 + fk16);
      __builtin_amdgcn_s_setprio(1);
#pragma unroll
      for (int mi = 0; mi < 4; ++mi)
#pragma unroll
        for (int ni = 0; ni < 4; ++ni)
          acc[mi][ni] = __builtin_amdgcn_mfma_f32_16x16x32_bf16(av[mi], bv[ni],
                                                                acc[mi][ni], 0, 0, 0);
      __builtin_amdgcn_s_setprio(0);
    }
    RAW_BAR();
    if (kt + 2 < ksteps) {
      stage_tile(A  + (kt + 2) * 64, lda, t, (kt & 1) ? lA1 : lA0);
      stage_tile(Bm + (kt + 2) * 64, ldb, t, (kt & 1) ? lB1 : lB0);
    }
  }
}

// ---------------- 128x64 half-tile GEMM core (scores): vmcnt(6), 48KB LDS ----
__device__ __forceinline__ void stage_btile(const uint16_t* __restrict__ g, int ld,
                                            int t, char* lds) {
#pragma unroll
  for (int c = 0; c < 2; ++c) {
    int L = c * 4096 + t * 16;
    int row = L >> 7;
    int slot = (t & 7) ^ (row & 7);
    gll16((const void*)(g + (size_t)row * ld + slot * 8), (void*)(lds + L));
  }
}

__device__ __forceinline__ void gemm_loop_h(const uint16_t* __restrict__ A, int lda,
                                            const uint16_t* __restrict__ Bm, int ldb,
                                            int ksteps, char* lds, f32x4 acc[4][2]) {
  char* lA0 = lds;          char* lA1 = lds + 16384;
  char* lB0 = lds + 32768;  char* lB1 = lds + 40960;
  const int t = threadIdx.x;
  const int lane = t & 63;
  const int wm = (t >> 6) & 1;                  // 64-row strip
  const int wn = t >> 7;                        // 32-col strip (0..1)
  const int frow = lane & 15;
  const int fk16 = (lane >> 4) * 16;

  stage_tile(A, lda, t, lA0); stage_btile(Bm, ldb, t, lB0);
  if (ksteps > 1) { stage_tile(A + 64, lda, t, lA1); stage_btile(Bm + 64, ldb, t, lB1); }

  for (int kt = 0; kt < ksteps; ++kt) {
    if (kt == ksteps - 1) { VM_WAIT0(); } else { VM_WAIT6(); }
    RAW_BAR();
    const char* cA = (kt & 1) ? lA1 : lA0;
    const char* cB = (kt & 1) ? lB1 : lB0;
#pragma unroll
    for (int ki = 0; ki < 2; ++ki) {
      bf16x8 av[4], bv[2];
#pragma unroll
      for (int mi = 0; mi < 4; ++mi)
        av[mi] = frag_ld(cA, wm * 64 + mi * 16 + frow, ki * 64 + fk16);
#pragma unroll
      for (int ni = 0; ni < 2; ++ni)
        bv[ni] = frag_ld(cB, wn * 32 + ni * 16 + frow, ki * 64 + fk16);
      __builtin_amdgcn_s_setprio(1);
#pragma unroll
      for (int mi = 0; mi < 4; ++mi)
#pragma unroll
        for (int ni = 0; ni < 2; ++ni)
          acc[mi][ni] = __builtin_amdgcn_mfma_f32_16x16x32_bf16(av[mi], bv[ni],
                                                                acc[mi][ni], 0, 0, 0);
      __builtin_amdgcn_s_setprio(0);
    }
    RAW_BAR();
    if (kt + 2 < ksteps) {
      stage_tile (A  + (kt + 2) * 64, lda, t, (kt & 1) ? lA1 : lA0);
      stage_btile(Bm + (kt + 2) * 64, ldb, t, (kt & 1) ? lB1 : lB0);
    }
  }
}

// ---------------- QKV projection: fused 8192x3072, 128^2 tiles, 2 blocks/CU --
// Grid 1536 = 64 m x 24 n, m-FASTEST, no swizzle: id mod 8 = XCD and 64*nt
// mod 8 == 0 -> each XCD only touches m-tiles with mt mod 8 == xcd: X slice
// stays L2-resident (proven: FETCH 47MB vs 200MB swizzled).
__global__ __launch_bounds__(256) void k_qkv(const uint16_t* __restrict__ Xbf,
                                             const uint16_t* __restrict__ Wbf,
                                             uint16_t* __restrict__ Qb,
                                             uint16_t* __restrict__ Kb,
                                             uint16_t* __restrict__ Vt) {
  __shared__ __align__(16) char lds[65536];
  int id = blockIdx.x;
  const int mt = id & 63, nt = id >> 6;
  const int m0 = mt * 128, n0 = nt * 128;
  const int g = n0 >> 10, ncol = n0 & 1023;

  f32x4 acc[4][4];
#pragma unroll
  for (int i = 0; i < 4; ++i)
#pragma unroll
    for (int j = 0; j < 4; ++j) acc[i][j] = (f32x4){0.f, 0.f, 0.f, 0.f};

  const uint16_t* A  = Xbf + (size_t)m0 * DIM;
  const uint16_t* Bm = Wbf + (size_t)n0 * DIM;  // Wbf as [3072][1024]
  gemm_loop(A, DIM, Bm, DIM, DIM / 64, lds, acc);

  const int lane = threadIdx.x & 63;
  const int wm = (threadIdx.x >> 6) & 1, wn = threadIdx.x >> 7;
  const int rbase = wm * 64 + (lane >> 4) * 4;  // C row = (lane>>4)*4 + reg
  const int cbase = wn * 64 + (lane & 15);      // C col = lane&15

  if (g < 2) {
    uint16_t* out = (g == 0) ? Qb : Kb;
#pragma unroll
    for (int mi = 0; mi < 4; ++mi)
#pragma unroll
      for (int ni = 0; ni < 4; ++ni) {
        int c = ncol + cbase + ni * 16;
#pragma unroll
        for (int r = 0; r < 4; ++r) {
          int m = m0 + rbase + mi * 16 + r;
          out[(size_t)m * DIM + c] = f2bf(acc[mi][ni][r]);
        }
      }
  } else {
    // write V transposed: Vt[b][e][s]
    const int b = m0 >> 11, sl = m0 & 2047;
#pragma unroll
    for (int mi = 0; mi < 4; ++mi)
#pragma unroll
      for (int ni = 0; ni < 4; ++ni) {
        int e = ncol + cbase + ni * 16;
        int s = sl + rbase + mi * 16;
        ushort4 o;
        o.x = f2bf(acc[mi][ni][0]); o.y = f2bf(acc[mi][ni][1]);
        o.z = f2bf(acc[mi][ni][2]); o.w = f2bf(acc[mi][ni][3]);
        *(ushort4*)(Vt + ((size_t)b * DIM + e) * SEQ + s) = o;
      }
  }
}

// ---------------- causal scores: Sc = Q K^T, 128x64 half-tile jobs, fp16 -----
// XCD-aware decode: id mod 8 = p = qt-PAIR index {p, 15-p} (pairs sum to 34
// half-jobs -> all 8 XCDs get exactly 136 jobs). Within an XCD, b-major so the
// live Q working set is one batch's panels (~512KB, L2-resident); the 8 XCDs
// no longer cross-fetch each other's Q/K panels from HBM.
__global__ __launch_bounds__(256) void k_scores(const uint16_t* __restrict__ Qb,
                                                const uint16_t* __restrict__ Kb,
                                                __half* __restrict__ Sc) {
  __shared__ __align__(16) char lds[49152];
  int id = blockIdx.x;                // 0..1087
  int p = id & 7;                     // XCD residue = qt-pair
  int w = id >> 3;                    // 0..135
  int b = w / 34;
  int l = w % 34;
  int thr = (p + 1) * 2;
  int qt, hk;
  if (l < thr) { qt = p;      hk = l; }
  else         { qt = 15 - p; hk = l - thr; }
  int kt = hk >> 1, nh = hk & 1;

  f32x4 acc[4][2];
#pragma unroll
  for (int i = 0; i < 4; ++i)
#pragma unroll
    for (int jj = 0; jj < 2; ++jj) acc[i][jj] = (f32x4){0.f, 0.f, 0.f, 0.f};

  const uint16_t* A  = Qb + ((size_t)b * SEQ + qt * 128) * DIM;
  const uint16_t* Bm = Kb + ((size_t)b * SEQ + kt * 128 + nh * 64) * DIM;
  gemm_loop_h(A, DIM, Bm, DIM, DIM / 64, lds, acc);

  const int lane = threadIdx.x & 63;
  const int wm = (threadIdx.x >> 6) & 1, wn = threadIdx.x >> 7;
  const int rbase = qt * 128 + wm * 64 + (lane >> 4) * 4;
  const int cbase = kt * 128 + nh * 64 + wn * 32 + (lane & 15);
  __half* out = Sc + (size_t)b * SEQ * SEQ;
#pragma unroll
  for (int mi = 0; mi < 4; ++mi)
#pragma unroll
    for (int ni = 0; ni < 2; ++ni) {
      int c = cbase + ni * 16;
#pragma unroll
      for (int r = 0; r < 4; ++r)
        out[(size_t)(rbase + mi * 16 + r) * SEQ + c] = __float2half(acc[mi][ni][r]);
    }
}

// ---------------- row softmax: one WAVE per row, fp16 row in registers -------
struct h4 { __half2 a, b; };          // 8 bytes = 4 halves

__global__ __launch_bounds__(256) void k_softmax(const __half* __restrict__ Sc,
                                                 uint16_t* __restrict__ P) {
  int gid = blockIdx.x * 4 + (threadIdx.x >> 6);
  int lane = threadIdx.x & 63;
  int b = gid >> 11, q = gid & 2047;
  const __half* srow = Sc + ((size_t)b * SEQ + q) * SEQ;
  uint16_t* prow = P + ((size_t)b * SEQ + q) * SEQ;
  int nv = q + 1;
  int kpad = ((q >> 7) + 1) << 7;     // PV reads exactly [0, kpad)
  int niter = (kpad + 255) >> 8;      // 256 halves per wave-iter

  float4 v[8];
  const h4* src = (const h4*)srow;
#pragma unroll
  for (int i = 0; i < 8; ++i) {
    if (i < niter) {
      int idx = lane + (i << 6);
      h4 raw = src[idx];
      float2 fa = __half22float2(raw.a), fb = __half22float2(raw.b);
      int k0 = idx << 2;
      float4 x;
      x.x = (k0 + 0 < nv) ? fa.x : -1e38f;
      x.y = (k0 + 1 < nv) ? fa.y : -1e38f;
      x.z = (k0 + 2 < nv) ? fb.x : -1e38f;
      x.w = (k0 + 3 < nv) ? fb.y : -1e38f;
      v[i] = x;
    } else {
      v[i] = make_float4(-1e38f, -1e38f, -1e38f, -1e38f);
    }
  }
  float m = -1e38f;
#pragma unroll
  for (int i = 0; i < 8; ++i)
    m = fmaxf(m, fmaxf(fmaxf(v[i].x, v[i].y), fmaxf(v[i].z, v[i].w)));
#pragma unroll
  for (int o = 32; o > 0; o >>= 1) m = fmaxf(m, __shfl_xor(m, o));

  float s = 0.f;
#pragma unroll
  for (int i = 0; i < 8; ++i) {
    v[i].x = __expf(v[i].x - m); v[i].y = __expf(v[i].y - m);
    v[i].z = __expf(v[i].z - m); v[i].w = __expf(v[i].w - m);
    s += v[i].x + v[i].y + v[i].z + v[i].w;
  }
#pragma unroll
  for (int o = 32; o > 0; o >>= 1) s += __shfl_xor(s, o);
  float inv = 1.0f / s;

  ushort4* dst = (ushort4*)prow;
#pragma unroll
  for (int i = 0; i < 8; ++i) {
    if (i < niter) {
      int idx = lane + (i << 6);
      if ((idx << 2) < kpad) {
        ushort4 o;
        o.x = f2bf(v[i].x * inv); o.y = f2bf(v[i].y * inv);
        o.z = f2bf(v[i].z * inv); o.w = f2bf(v[i].w * inv);
        dst[idx] = o;
      }
    }
  }
}

// ---------------- PV: O = P V  (A=P, B=Vt rows=e, cols=k) ----------------
// XCD-aware decode: id mod 8 = b*2 + (qt&1) -> each XCD hosts ONE batch's Vt
// (4MB, L2-resident) and each P panel is consumed by all 8 et-blocks on the
// SAME XCD (P HBM traffic ~139MB -> ~17MB). Blocks id and id+256 (same CU,
// proven pairing distance from R7) get complementary qt -> 34/38 K-steps/CU.
__global__ __launch_bounds__(256) void k_pv(const uint16_t* __restrict__ P,
                                            const uint16_t* __restrict__ Vt,
                                            float* __restrict__ O) {
  __shared__ __align__(16) char lds[65536];
  int id = blockIdx.x;                // 0..511
  int lo = id & 7;
  int b = lo >> 1, parity = lo & 1;
  int w = id >> 3;                    // 0..63
  int et = w >> 3, a = w & 7;
  int qt = 2 * ((et < 4) ? a : (7 - a)) + parity;

  f32x4 acc[4][4];
#pragma unroll
  for (int i = 0; i < 4; ++i)
#pragma unroll
    for (int j = 0; j < 4; ++j) acc[i][j] = (f32x4){0.f, 0.f, 0.f, 0.f};

  const uint16_t* A = P + (size_t)b * SEQ * SEQ + (size_t)qt * 128 * SEQ;
  const uint16_t* Bm = Vt + (size_t)b * DIM * SEQ + (size_t)et * 128 * SEQ;
  gemm_loop(A, SEQ, Bm, SEQ, (qt + 1) * 2, lds, acc);

  const int lane = threadIdx.x & 63;
  const int wm = (threadIdx.x >> 6) & 1, wn = threadIdx.x >> 7;
  const int rbase = qt * 128 + wm * 64 + (lane >> 4) * 4;
  const int cbase = et * 128 + wn * 64 + (lane & 15);
  float* out = O + (size_t)b * SEQ * DIM;
#pragma unroll
  for (int mi = 0; mi < 4; ++mi)
#pragma unroll
    for (int ni = 0; ni < 4; ++ni) {
      int c = cbase + ni * 16;
#pragma unroll
      for (int r = 0; r < 4; ++r)
        out[(size_t)(rbase + mi * 16 + r) * DIM + c] = acc[mi][ni][r];
    }
}

extern "C" void kernel_launch(void* const* d_in, const int* in_sizes, int n_in,
                              void* d_out, int out_size, void* d_ws, size_t ws_size,
                              hipStream_t stream) {
  const float* X  = (const float*)d_in[0];
  const float* Wq = (const float*)d_in[1];
  const float* Wk = (const float*)d_in[2];
  const float* Wv = (const float*)d_in[3];
  char* ws = (char*)d_ws;
  uint16_t* Xbf = (uint16_t*)(ws + OFF_XBF);
  uint16_t* Wbf = (uint16_t*)(ws + OFF_WBF);
  uint16_t* Qb  = (uint16_t*)(ws + OFF_Q);
  uint16_t* Kb  = (uint16_t*)(ws + OFF_K);
  uint16_t* Vt  = (uint16_t*)(ws + OFF_VT);
  __half*   Sc  = (__half*)(ws + OFF_SC);
  uint16_t* P   = (uint16_t*)(ws + OFF_P);
  float*    O   = (float*)d_out;

  k_convert<<<11264, 256, 0, stream>>>(X, Wq, Wk, Wv, Xbf, Wbf);
  k_qkv<<<1536, 256, 0, stream>>>(Xbf, Wbf, Qb, Kb, Vt);
  k_scores<<<1088, 256, 0, stream>>>(Qb, Kb, Sc);
  k_softmax<<<2048, 256, 0, stream>>>(Sc, P);
  k_pv<<<512, 256, 0, stream>>>(P, Vt, O);
}